// Round 1
// baseline (197.345 us; speedup 1.0000x reference)
//
#include <hip/hip_runtime.h>

#define IN_FEATURES 512
#define GRID_COLS   12   // grid_size + 2*order + 1 = 5 + 6 + 1
#define OUT_PER     8    // grid_size + order = 5 + 3

__global__ __launch_bounds__(256) void bspline_basis_kernel(
    const float* __restrict__ x,
    const float* __restrict__ grid,
    float* __restrict__ out,
    int total)
{
    int tid    = blockIdx.x * blockDim.x + threadIdx.x;
    int stride = gridDim.x * blockDim.x;

    for (int e = tid; e < total; e += stride) {
        int feat = e & (IN_FEATURES - 1);
        float xv = x[e];

        // grid row for this feature (all rows identical, but follow reference)
        const float* g = grid + feat * GRID_COLS;
        float g3 = g[3];            // first in-range knot (= -0.5)
        float h  = g[4] - g3;       // uniform spacing (= 0.4)

        // locate knot interval: j = 3 + jo, jo = floor((x - g3)/h)
        float u  = (xv - g3) / h;
        float fj = floorf(u);
        int jo = (int)fj;
        jo = jo < 0 ? 0 : (jo > 4 ? 4 : jo);   // keep outputs in [0,7]
        float t = u - (float)jo;               // local coordinate in [0,1)

        // uniform cubic B-spline basis values (nonzero bases jo .. jo+3)
        float omt  = 1.0f - t;
        float t2   = t * t;
        float t3   = t2 * t;
        float omt3 = omt * omt * omt;
        const float k6 = 1.0f / 6.0f;
        float b0 = omt3 * k6;
        float b1 = (3.0f * t3 - 6.0f * t2 + 4.0f) * k6;
        float b2 = (-3.0f * t3 + 3.0f * t2 + 3.0f * t + 1.0f) * k6;
        float b3 = t3 * k6;

        // assemble 8-wide output in registers (constant indices only)
        float v[OUT_PER];
        #pragma unroll
        for (int m = 0; m < OUT_PER; ++m) {
            int s = m - jo;
            float val = 0.0f;
            val = (s == 0) ? b0 : val;
            val = (s == 1) ? b1 : val;
            val = (s == 2) ? b2 : val;
            val = (s == 3) ? b3 : val;
            v[m] = val;
        }

        float4* o4 = reinterpret_cast<float4*>(out + (size_t)e * OUT_PER);
        o4[0] = make_float4(v[0], v[1], v[2], v[3]);
        o4[1] = make_float4(v[4], v[5], v[6], v[7]);
    }
}

extern "C" void kernel_launch(void* const* d_in, const int* in_sizes, int n_in,
                              void* d_out, int out_size, void* d_ws, size_t ws_size,
                              hipStream_t stream) {
    const float* x    = (const float*)d_in[0];
    const float* grid = (const float*)d_in[1];
    float* out        = (float*)d_out;

    int total = in_sizes[0];               // N * IN_FEATURES = 16,777,216
    int threads = 256;
    int blocks = (total + threads - 1) / threads;
    if (blocks > 4096) blocks = 4096;      // grid-stride; 256 CUs * 16 blocks

    bspline_basis_kernel<<<blocks, threads, 0, stream>>>(x, grid, out, total);
}

// Round 2
// 162.821 us; speedup vs baseline: 1.2120x; 1.2120x over previous
//
#include <hip/hip_runtime.h>

#define IN_FEATURES 512
#define GRID_COLS   12   // grid_size + 2*order + 1 = 5 + 6 + 1
#define OUT_PER     8    // grid_size + order = 5 + 3

// One thread per 16-byte output chunk (2 chunks per element).
// Adjacent lanes duplicate the (cheap) basis compute; every wave store is a
// fully contiguous 1 KB segment -> full store-path efficiency.
__global__ __launch_bounds__(256) void bspline_basis_kernel(
    const float* __restrict__ x,
    const float* __restrict__ grid,
    float4* __restrict__ out4,
    int total_chunks)
{
    int tid    = blockIdx.x * blockDim.x + threadIdx.x;
    int stride = gridDim.x * blockDim.x;

    for (int c = tid; c < total_chunks; c += stride) {
        int e    = c >> 1;           // element index
        int half = c & 1;            // which float4 of the 8-wide row
        int feat = e & (IN_FEATURES - 1);
        float xv = x[e];

        const float* g = grid + feat * GRID_COLS;
        float g3 = g[3];             // first in-range knot (= -0.5)
        float h  = g[4] - g3;        // uniform spacing (= 0.4)

        // knot interval: jo = clamp(floor((x - g3)/h), 0, 4)
        float u  = (xv - g3) / h;
        float fj = floorf(u);
        int jo = (int)fj;
        jo = jo < 0 ? 0 : (jo > 4 ? 4 : jo);
        float t = u - (float)jo;     // local coordinate in [0,1)

        // uniform cubic B-spline basis (nonzero bases jo .. jo+3)
        float omt  = 1.0f - t;
        float t2   = t * t;
        float t3   = t2 * t;
        float omt3 = omt * omt * omt;
        const float k6 = 1.0f / 6.0f;
        float b0 = omt3 * k6;
        float b1 = (3.0f * t3 - 6.0f * t2 + 4.0f) * k6;
        float b2 = (-3.0f * t3 + 3.0f * t2 + 3.0f * t + 1.0f) * k6;
        float b3 = t3 * k6;

        // this thread's 4 outputs: m = half*4 + 0..3 ; value b_{m-jo} if 0<=m-jo<=3
        int m0 = half << 2;
        float v[4];
        #pragma unroll
        for (int q = 0; q < 4; ++q) {
            int s = (m0 + q) - jo;
            float val = 0.0f;
            val = (s == 0) ? b0 : val;
            val = (s == 1) ? b1 : val;
            val = (s == 2) ? b2 : val;
            val = (s == 3) ? b3 : val;
            v[q] = val;
        }

        out4[c] = make_float4(v[0], v[1], v[2], v[3]);
    }
}

extern "C" void kernel_launch(void* const* d_in, const int* in_sizes, int n_in,
                              void* d_out, int out_size, void* d_ws, size_t ws_size,
                              hipStream_t stream) {
    const float* x    = (const float*)d_in[0];
    const float* grid = (const float*)d_in[1];
    float4* out4      = (float4*)d_out;

    int total_chunks = in_sizes[0] * 2;    // (N*IN) elements * 2 chunks each
    int threads = 256;
    int blocks = (total_chunks + threads - 1) / threads;
    if (blocks > 4096) blocks = 4096;      // grid-stride

    bspline_basis_kernel<<<blocks, threads, 0, stream>>>(x, grid, out4, total_chunks);
}

// Round 4
// 139.645 us; speedup vs baseline: 1.4132x; 1.1660x over previous
//
#include <hip/hip_runtime.h>

#define IN_FEATURES 512
#define GRID_COLS   12   // grid_size + 2*order + 1 = 5 + 6 + 1
#define OUT_PER     8    // grid_size + order = 5 + 3

typedef float f32x4 __attribute__((ext_vector_type(4)));

// One thread per 16-byte output chunk (2 chunks per element).
// grid-row lookup is loop-invariant (stride multiple of 1024 chunks = 512
// elements), so all grid loads + the divide are hoisted out of the loop.
// Non-temporal loads/stores: both streams have zero reuse.
__global__ __launch_bounds__(256) void bspline_basis_kernel(
    const float* __restrict__ x,
    const float* __restrict__ grid,
    f32x4* __restrict__ out4,
    int total_chunks)
{
    int tid    = blockIdx.x * blockDim.x + threadIdx.x;
    int stride = gridDim.x * blockDim.x;   // multiple of 1024 (blocks % 4 == 0)

    // feat is invariant across the grid-stride loop: e advances by stride/2,
    // a multiple of 512, so e & 511 never changes.
    int feat = (tid >> 1) & (IN_FEATURES - 1);
    const float* g = grid + feat * GRID_COLS;
    float g3    = g[3];          // first in-range knot (= -0.5)
    float h     = g[4] - g3;     // uniform spacing (= 0.4)
    float inv_h = 1.0f / h;

    for (int c = tid; c < total_chunks; c += stride) {
        int e    = c >> 1;           // element index
        int half = c & 1;            // which float4 of the 8-wide row
        float xv = __builtin_nontemporal_load(x + e);

        // knot interval: jo = clamp(floor((x - g3)/h), 0, 4)
        float u  = (xv - g3) * inv_h;
        float fj = floorf(u);
        int jo = (int)fj;
        jo = jo < 0 ? 0 : (jo > 4 ? 4 : jo);
        float t = u - (float)jo;     // local coordinate in [0,1)

        // uniform cubic B-spline basis (nonzero bases jo .. jo+3)
        float omt  = 1.0f - t;
        float t2   = t * t;
        float t3   = t2 * t;
        float omt3 = omt * omt * omt;
        const float k6 = 1.0f / 6.0f;
        float b0 = omt3 * k6;
        float b1 = (3.0f * t3 - 6.0f * t2 + 4.0f) * k6;
        float b2 = (-3.0f * t3 + 3.0f * t2 + 3.0f * t + 1.0f) * k6;
        float b3 = t3 * k6;

        // this thread's 4 outputs: m = half*4 + q ; value b_{m-jo} if in [0,3]
        int m0 = half << 2;
        float v[4];
        #pragma unroll
        for (int q = 0; q < 4; ++q) {
            int s = (m0 + q) - jo;
            float val = 0.0f;
            val = (s == 0) ? b0 : val;
            val = (s == 1) ? b1 : val;
            val = (s == 2) ? b2 : val;
            val = (s == 3) ? b3 : val;
            v[q] = val;
        }

        f32x4 res = { v[0], v[1], v[2], v[3] };
        __builtin_nontemporal_store(res, out4 + c);
    }
}

extern "C" void kernel_launch(void* const* d_in, const int* in_sizes, int n_in,
                              void* d_out, int out_size, void* d_ws, size_t ws_size,
                              hipStream_t stream) {
    const float* x    = (const float*)d_in[0];
    const float* grid = (const float*)d_in[1];
    f32x4* out4       = (f32x4*)d_out;

    int total_chunks = in_sizes[0] * 2;    // (N*IN) elements * 2 chunks each
    int threads = 256;
    int blocks = (total_chunks + threads - 1) / threads;
    if (blocks > 4096) blocks = 4096;      // grid-stride
    blocks = (blocks + 3) & ~3;            // keep stride a multiple of 1024

    bspline_basis_kernel<<<blocks, threads, 0, stream>>>(x, grid, out4, total_chunks);
}